// Round 1
// 162.955 us; speedup vs baseline: 1.0317x; 1.0317x over previous
//
#include <hip/hip_runtime.h>

#define BSZ 64
#define SEQ 512
#define HD  768
#define TT  64     // topic/token list length
#define NPART 8    // blocks per batch
#define TPP 16     // topic/token tasks per part (64 / 4 parts)

// ---------------------------------------------------------------------------
// Fused kernel: one launch.
// grid = 64 batches x 8 parts = 512 blocks x 256 threads (4 waves/block).
//   part 0   : cls task + topic tasks l=0..15   (needs V rows 0..3)
//   parts 1-3: topic tasks l=p*16..p*16+15      (needs V rows 2,3)
//   parts 4-7: token tasks l=(p-4)*16..+15      (needs V rows 4,5)
// V rows (effective weights) are computed into LDS per block:
//   V[w*2+o][m*8+c] = sum_a dom[m*8+a] * W_w[o][m*64+a*8+c]
// Then each wave does per-task dot products: hidden row (global, coalesced
// float4) x V rows (LDS). No global Vg round-trip, no second launch.
// ---------------------------------------------------------------------------
__global__ __launch_bounds__(256) void fused_kernel(
    const float* __restrict__ hidden,     // [64,512,768]
    const float* __restrict__ Wsrc,       // [862,384]
    const float* __restrict__ Wtgt,       // [862,384]
    const float* __restrict__ W_cls,      // [2,6144]
    const float* __restrict__ W_topic,    // [2,6144]
    const float* __restrict__ W_token,    // [2,6144]
    const float* __restrict__ b_cls,      // [2]
    const float* __restrict__ b_topic,    // [2]
    const float* __restrict__ b_token,    // [2]
    const int*   __restrict__ source_ids, // [64]
    const int*   __restrict__ target_ids, // [64]
    const int*   __restrict__ topic_inds, // [64,64]
    const float* __restrict__ topic_mask, // [64,64]
    const int*   __restrict__ token_inds, // [64,64]
    const float* __restrict__ token_mask, // [64,64]
    float*       __restrict__ out)        // [128 + 8192 + 8192]
{
    __shared__ __align__(16) float dom[HD];
    __shared__ __align__(16) float Vl[4][HD];   // 12 KB; +3 KB dom = 15 KB LDS

    const int blk = blockIdx.x;
    const int b   = blk >> 3;      // batch
    const int p   = blk & 7;       // part
    const int tid = threadIdx.x;

    // ---- stage domain embedding -------------------------------------------
    const int sid = source_ids[b];
    const int tgt = target_ids[b];
    for (int j = tid; j < HD; j += 256)
        dom[j] = (j < 384) ? Wsrc[sid * 384 + j] : Wtgt[tgt * 384 + (j - 384)];
    __syncthreads();

    // ---- compute the V rows this part needs into LDS ----------------------
    int base_row, nrows;
    if (p == 0)      { base_row = 0; nrows = 4; }   // cls (0,1) + topic (2,3)
    else if (p < 4)  { base_row = 2; nrows = 2; }   // topic
    else             { base_row = 4; nrows = 2; }   // token

    for (int idx = tid; idx < nrows * HD; idx += 256) {
        const int ri = idx / HD;
        const int d  = idx - ri * HD;
        const int r  = base_row + ri;               // global row id w*2+o
        const int w  = r >> 1, o = r & 1;
        const float* Wp = (w == 0) ? W_cls : (w == 1) ? W_topic : W_token;
        const int m = d >> 3, c = d & 7;
        const float* wrow = Wp + o * 6144 + m * 64 + c;
        float acc = 0.f;
        #pragma unroll
        for (int a = 0; a < 8; ++a)
            acc = fmaf(dom[m * 8 + a], wrow[a * 8], acc);
        Vl[ri][d] = acc;
    }
    __syncthreads();

    // ---- task loop: 4 waves, tasks strided by wave id ---------------------
    const int wid  = tid >> 6;
    const int lane = tid & 63;
    const int ntasks = (p == 0) ? (1 + TPP) : TPP;

    for (int ti = wid; ti < ntasks; ti += 4) {
        int pos, outoff, vbase;
        float mask;
        const float* bias;
        bool do_softmax;
        if (p == 0 && ti == 0) {                    // cls
            pos = 0; mask = 1.f; bias = b_cls; do_softmax = true;
            outoff = b * 2; vbase = 0;
        } else if (p < 4) {                         // topic
            const int l = (p == 0) ? (ti - 1) : (p * TPP + ti);
            pos = topic_inds[b * TT + l]; mask = topic_mask[b * TT + l];
            bias = b_topic; do_softmax = true;
            outoff = 128 + (b * TT + l) * 2;
            vbase = (p == 0) ? 2 : 0;
        } else {                                    // token
            const int l = (p - 4) * TPP + ti;
            pos = token_inds[b * TT + l]; mask = token_mask[b * TT + l];
            bias = b_token; do_softmax = false;
            outoff = 128 + BSZ * TT * 2 + (b * TT + l) * 2;
            vbase = 0;
        }

        const float4* hrow = reinterpret_cast<const float4*>(
            hidden + ((size_t)b * SEQ + (size_t)pos) * HD);
        const float4* v0 = reinterpret_cast<const float4*>(&Vl[vbase][0]);
        const float4* v1 = reinterpret_cast<const float4*>(&Vl[vbase + 1][0]);

        float a0 = 0.f, a1 = 0.f;
        #pragma unroll
        for (int k = 0; k < 3; ++k) {               // 768 floats = 64 lanes x 3 float4
            const float4 h4 = hrow[lane + k * 64];
            const float4 x0 = v0[lane + k * 64];
            const float4 x1 = v1[lane + k * 64];
            a0 = fmaf(h4.x, x0.x, a0); a1 = fmaf(h4.x, x1.x, a1);
            a0 = fmaf(h4.y, x0.y, a0); a1 = fmaf(h4.y, x1.y, a1);
            a0 = fmaf(h4.z, x0.z, a0); a1 = fmaf(h4.z, x1.z, a1);
            a0 = fmaf(h4.w, x0.w, a0); a1 = fmaf(h4.w, x1.w, a1);
        }
        #pragma unroll
        for (int off = 32; off > 0; off >>= 1) {
            a0 += __shfl_down(a0, off, 64);
            a1 += __shfl_down(a1, off, 64);
        }

        if (lane == 0) {
            const float l0 = fmaf(mask, a0, bias[0]);
            const float l1 = fmaf(mask, a1, bias[1]);
            if (do_softmax) {
                const float mx = fmaxf(l0, l1);
                const float e0 = __expf(l0 - mx);
                const float e1 = __expf(l1 - mx);
                const float inv = 1.f / (e0 + e1);
                out[outoff]     = e0 * inv;
                out[outoff + 1] = e1 * inv;
            } else {
                out[outoff]     = l0;
                out[outoff + 1] = l1;
            }
        }
    }
}

extern "C" void kernel_launch(void* const* d_in, const int* in_sizes, int n_in,
                              void* d_out, int out_size, void* d_ws, size_t ws_size,
                              hipStream_t stream) {
    const float* hidden     = (const float*)d_in[0];
    const float* Wsrc       = (const float*)d_in[1];
    const float* Wtgt       = (const float*)d_in[2];
    const float* W_cls      = (const float*)d_in[3];
    const float* b_cls      = (const float*)d_in[4];
    const float* W_topic    = (const float*)d_in[5];
    const float* b_topic    = (const float*)d_in[6];
    const float* W_token    = (const float*)d_in[7];
    const float* b_token    = (const float*)d_in[8];
    const int*   source_ids = (const int*)d_in[9];
    const int*   target_ids = (const int*)d_in[10];
    // d_in[11] ent_inds, d_in[12] ent_mask: dead in reference (never used)
    const int*   topic_inds = (const int*)d_in[13];
    const float* topic_mask = (const float*)d_in[14];
    const int*   token_inds = (const int*)d_in[15];
    const float* token_mask = (const float*)d_in[16];
    float* out = (float*)d_out;

    fused_kernel<<<BSZ * NPART, 256, 0, stream>>>(
        hidden, Wsrc, Wtgt, W_cls, W_topic, W_token,
        b_cls, b_topic, b_token, source_ids, target_ids,
        topic_inds, topic_mask, token_inds, token_mask, out);
}